// Round 6
// baseline (36.696 us; speedup 1.0000x reference)
//
#include <hip/hip_runtime.h>
#include <hip/hip_bf16.h>
#include <cstdint>

#define NN 2048
#define FF 64
#define BCC 16

typedef float f32x4 __attribute__((ext_vector_type(4)));
typedef __bf16 bf16x8 __attribute__((ext_vector_type(8)));
typedef uint32_t u32x4 __attribute__((ext_vector_type(4)));

// ---------------- workspace layout (bytes) ----------------
// xP   : bf16 packed [16][jt=64][nb=4][lane=64][e=8] = 4,194,304  (off 0)
//        element (bc,jt,nb,(g,l15),e) = x[bc][n = jt*32+8g+e][f = nb*16+l15]
// U    : f32 [16][2048] = 131,072  (off 4,194,304)   e^{f2}
// V    : f32 [16][2048] = 131,072  (off 4,325,376)   e^{0.1 f2}
// CI   : f32 [16][2048] = 131,072  (off 4,456,448)   e^{-0.9 f1}
// ADJB : u8  [bj=256][row=2048] = 524,288 (off 4,587,520)  bj = j/8 bitmask byte
// AMSK : u32x4 [bj=256][row=2048] = 8,388,608 (off 5,111,808)
//        expanded 16B AND-mask for the 8 bf16 weights of (row, j in [8bj,8bj+8))

// fused prep: blocks [0,512): transpose/pack x + per-row dot/exp tables.
//             blocks [512,4608): adj -> transposed byte bitmask ADJB.
__global__ __launch_bounds__(256) void k_prep(const float* __restrict__ x,
        const int* __restrict__ adj,
        const float* __restrict__ a1, const float* __restrict__ a2,
        __hip_bfloat16* __restrict__ xP, float* __restrict__ U,
        float* __restrict__ V, float* __restrict__ CI,
        unsigned char* __restrict__ ADJB) {
    int wid  = threadIdx.x >> 6;
    int lane = threadIdx.x & 63;

    if (blockIdx.x >= 512) {                 // ---- adj packing ----
        int idx = (blockIdx.x - 512) * 4 + wid;   // row*8 + cg
        int row = idx >> 3, cg = idx & 7;
        const int* p = adj + (size_t)row * NN + cg * 256 + lane;
        unsigned long long m0 = __ballot(p[0]   > 0);
        unsigned long long m1 = __ballot(p[64]  > 0);
        unsigned long long m2 = __ballot(p[128] > 0);
        unsigned long long m3 = __ballot(p[192] > 0);
        if (lane < 32) {
            unsigned long long m = (lane < 8) ? m0 : (lane < 16) ? m1
                                 : (lane < 24) ? m2 : m3;
            unsigned char byte = (unsigned char)(m >> (8 * (lane & 7)));
            ADJB[(size_t)(cg * 32 + lane) * NN + row] = byte;
        }
        return;
    }

    // ---- x pack + tables ----
    __shared__ float tile[64][65];
    __shared__ float red[2][64][4];
    int bc = blockIdx.x >> 5;
    int n0 = (blockIdx.x & 31) * 64;
    int tx = lane;
    int ty = wid;
    const float* xp = x + ((size_t)bc * NN + n0) * FF;
    #pragma unroll
    for (int k = 0; k < 16; k++) {
        int nl = ty * 16 + k;
        tile[nl][tx] = xp[(size_t)nl * FF + tx];
    }
    __syncthreads();
    // packed fragment-order write (coalesced 16B per lane)
    int g = lane >> 4, l15 = lane & 15;
    int jt0 = n0 >> 5;
    #pragma unroll
    for (int jl = 0; jl < 2; jl++) {
        bf16x8 val;
        #pragma unroll
        for (int e = 0; e < 8; e++)
            val[e] = (__bf16)tile[jl * 32 + 8 * g + e][ty * 16 + l15];
        ((bf16x8*)xP)[(((size_t)bc * 64 + jt0 + jl) * 4 + ty) * 64 + lane] = val;
    }
    // dots: thread handles row tx, f-quarter ty
    float d1 = 0.f, d2 = 0.f;
    #pragma unroll
    for (int i = 0; i < 16; i++) {
        int f = ty * 16 + i;
        float xv = tile[tx][f];
        d1 += xv * a1[f];
        d2 += xv * a2[f];
    }
    red[0][tx][ty] = d1;
    red[1][tx][ty] = d2;
    __syncthreads();
    if (ty == 0) {
        float f1 = red[0][tx][0] + red[0][tx][1] + red[0][tx][2] + red[0][tx][3];
        float f2 = red[1][tx][0] + red[1][tx][1] + red[1][tx][2] + red[1][tx][3];
        int idx = bc * NN + n0 + tx;
        U[idx]  = expf(f2);
        V[idx]  = expf(0.1f * f2);
        CI[idx] = expf(-0.9f * f1);
    }
}

// expand packed bytes to 16B bf16-pair AND masks (coalesced both sides)
__global__ __launch_bounds__(256) void k_expand(
        const unsigned char* __restrict__ ADJB, u32x4* __restrict__ AMSK) {
    int idx = blockIdx.x * 256 + threadIdx.x;   // bj*2048 + row
    uint32_t b = ADJB[idx];
    u32x4 m;
    #pragma unroll
    for (int w = 0; w < 4; w++)
        m[w] = (((b >> (2 * w)) & 1u) ? 0xFFFFu : 0u)
             | (((b >> (2 * w + 1)) & 1u) ? 0xFFFF0000u : 0u);
    AMSK[idx] = m;
}

union SmemT {
    struct { float u[2048]; float v[2048]; } s;                  // 16 KB
    struct { float part[4][64][68]; float z[4][64]; } e;         // 70.7 KB
};

// main: block = (bc, 64-row i-block); 4 waves, wave jq owns j-quarter (512 j).
// Each wave: 4 a-tiles (M=64) x 4 nb (F=64), 20 MFMA per jt.
// weights w' = adj * max(u_j, Ci*v_j)  (softmax row-scale invariance).
__global__ __launch_bounds__(256, 2) void k_main(
        const __hip_bfloat16* __restrict__ xP, const float* __restrict__ U,
        const float* __restrict__ V, const float* __restrict__ CI,
        const u32x4* __restrict__ AMSK, float* __restrict__ out) {
    __shared__ SmemT sm;

    int tid = threadIdx.x;
    int jq = tid >> 6, lane = tid & 63;
    int l15 = lane & 15, g = lane >> 4;

    // swizzle 512 blocks: XCD = (bc-group of 8) x (iblk-group of 8)
    int xcd = blockIdx.x & 7, t = blockIdx.x >> 3;   // t in 0..63
    int bc   = (xcd & 1) * 8 + (t >> 3);
    int iblk = (xcd >> 1) * 8 + (t & 7);
    int i0   = iblk * 64;

    // stage U/V into LDS (coalesced)
    const f32x4* Ug = (const f32x4*)(U + bc * NN);
    const f32x4* Vg = (const f32x4*)(V + bc * NN);
    ((f32x4*)sm.s.u)[tid]       = Ug[tid];
    ((f32x4*)sm.s.u)[tid + 256] = Ug[tid + 256];
    ((f32x4*)sm.s.v)[tid]       = Vg[tid];
    ((f32x4*)sm.s.v)[tid + 256] = Vg[tid + 256];

    float Ci[4];
    #pragma unroll
    for (int a = 0; a < 4; a++)
        Ci[a] = CI[bc * NN + i0 + 16 * a + l15];
    __syncthreads();

    f32x4 acc[4][4];
    #pragma unroll
    for (int a = 0; a < 4; a++)
        #pragma unroll
        for (int nb = 0; nb < 4; nb++)
            acc[a][nb] = (f32x4){0.f, 0.f, 0.f, 0.f};
    f32x4 accz[4];
    #pragma unroll
    for (int a = 0; a < 4; a++) accz[a] = (f32x4){0.f, 0.f, 0.f, 0.f};
    bf16x8 onesf;
    #pragma unroll
    for (int e = 0; e < 8; e++) onesf[e] = (__bf16)1.0f;

    const u32x4* xPbc = (const u32x4*)xP + (size_t)bc * 16384;

    // pipeline stage registers (named, static indexing only)
    u32x4 A_x0, A_x1, A_x2, A_x3, B_x0, B_x1, B_x2, B_x3;   // B fragments
    u32x4 A_m0, A_m1, A_m2, A_m3, B_m0, B_m1, B_m2, B_m3;   // adj masks

#define LOADS(P, J) do {                                                      \
        const u32x4* xw_ = xPbc + (((size_t)(jq * 16 + (J))) << 8) + lane;    \
        P##x0 = xw_[0]; P##x1 = xw_[64]; P##x2 = xw_[128]; P##x3 = xw_[192];  \
        const u32x4* mp_ = AMSK + ((size_t)((jq * 16 + (J)) * 4 + g)) * 2048  \
                         + i0 + l15;                                          \
        P##m0 = mp_[0]; P##m1 = mp_[16]; P##m2 = mp_[32]; P##m3 = mp_[48];    \
    } while (0)

#define COMP(P, J) do {                                                       \
        const int jo_ = (jq * 16 + (J)) * 32 + 8 * g;                         \
        f32x4 cu0 = *(const f32x4*)&sm.s.u[jo_];                              \
        f32x4 cu1 = *(const f32x4*)&sm.s.u[jo_ + 4];                          \
        f32x4 cv0 = *(const f32x4*)&sm.s.v[jo_];                              \
        f32x4 cv1 = *(const f32x4*)&sm.s.v[jo_ + 4];                          \
        _Pragma("unroll")                                                     \
        for (int a = 0; a < 4; a++) {                                         \
            bf16x8 af_;                                                       \
            _Pragma("unroll")                                                 \
            for (int tt = 0; tt < 8; tt++) {                                  \
                float uu = (tt < 4) ? cu0[tt] : cu1[tt - 4];                  \
                float vv = (tt < 4) ? cv0[tt] : cv1[tt - 4];                  \
                af_[tt] = (__bf16)fmaxf(uu, Ci[a] * vv);                      \
            }                                                                 \
            u32x4 mm = (a == 0) ? P##m0 : (a == 1) ? P##m1                    \
                     : (a == 2) ? P##m2 : P##m3;                              \
            af_ = __builtin_bit_cast(bf16x8,                                  \
                      __builtin_bit_cast(u32x4, af_) & mm);                   \
            acc[a][0] = __builtin_amdgcn_mfma_f32_16x16x32_bf16(af_,          \
                __builtin_bit_cast(bf16x8, P##x0), acc[a][0], 0, 0, 0);       \
            acc[a][1] = __builtin_amdgcn_mfma_f32_16x16x32_bf16(af_,          \
                __builtin_bit_cast(bf16x8, P##x1), acc[a][1], 0, 0, 0);       \
            acc[a][2] = __builtin_amdgcn_mfma_f32_16x16x32_bf16(af_,          \
                __builtin_bit_cast(bf16x8, P##x2), acc[a][2], 0, 0, 0);       \
            acc[a][3] = __builtin_amdgcn_mfma_f32_16x16x32_bf16(af_,          \
                __builtin_bit_cast(bf16x8, P##x3), acc[a][3], 0, 0, 0);       \
            accz[a]   = __builtin_amdgcn_mfma_f32_16x16x32_bf16(af_,          \
                onesf, accz[a], 0, 0, 0);                                     \
        }                                                                     \
    } while (0)

    LOADS(A_, 0);
    LOADS(B_, 1);  COMP(A_, 0);
    LOADS(A_, 2);  COMP(B_, 1);
    LOADS(B_, 3);  COMP(A_, 2);
    LOADS(A_, 4);  COMP(B_, 3);
    LOADS(B_, 5);  COMP(A_, 4);
    LOADS(A_, 6);  COMP(B_, 5);
    LOADS(B_, 7);  COMP(A_, 6);
    LOADS(A_, 8);  COMP(B_, 7);
    LOADS(B_, 9);  COMP(A_, 8);
    LOADS(A_, 10); COMP(B_, 9);
    LOADS(B_, 11); COMP(A_, 10);
    LOADS(A_, 12); COMP(B_, 11);
    LOADS(B_, 13); COMP(A_, 12);
    LOADS(A_, 14); COMP(B_, 13);
    LOADS(B_, 15); COMP(A_, 14);
    COMP(B_, 15);
#undef LOADS
#undef COMP

    __syncthreads();   // u/v staging dead; reuse LDS for epilogue

    #pragma unroll
    for (int a = 0; a < 4; a++)
        #pragma unroll
        for (int nb = 0; nb < 4; nb++)
            #pragma unroll
            for (int r = 0; r < 4; r++)
                sm.e.part[jq][16 * a + 4 * g + r][nb * 16 + l15] = acc[a][nb][r];
    if (l15 == 0) {
        #pragma unroll
        for (int a = 0; a < 4; a++)
            #pragma unroll
            for (int r = 0; r < 4; r++)
                sm.e.z[jq][16 * a + 4 * g + r] = accz[a][r];
    }
    __syncthreads();

    // wave jq reduces rows [16jq, 16jq+16): lane (g,l15) -> rows 4g+r, f-chunk l15
    float* outp = out + ((size_t)bc * NN + i0) * FF;
    #pragma unroll
    for (int r = 0; r < 4; r++) {
        int row = jq * 16 + g * 4 + r;
        f32x4 s = *(const f32x4*)&sm.e.part[0][row][l15 * 4];
        s = s + *(const f32x4*)&sm.e.part[1][row][l15 * 4];
        s = s + *(const f32x4*)&sm.e.part[2][row][l15 * 4];
        s = s + *(const f32x4*)&sm.e.part[3][row][l15 * 4];
        float zi = 1.0f / (sm.e.z[0][row] + sm.e.z[1][row]
                         + sm.e.z[2][row] + sm.e.z[3][row]);
        f32x4 o = s * zi;
        *(f32x4*)(outp + (size_t)row * FF + l15 * 4) = o;
    }
}

extern "C" void kernel_launch(void* const* d_in, const int* in_sizes, int n_in,
                              void* d_out, int out_size, void* d_ws, size_t ws_size,
                              hipStream_t stream) {
    const float* x  = (const float*)d_in[0];
    const int* adj  = (const int*)d_in[1];
    const float* a1 = (const float*)d_in[2];
    const float* a2 = (const float*)d_in[3];
    float* out = (float*)d_out;

    char* ws = (char*)d_ws;
    __hip_bfloat16* xP = (__hip_bfloat16*)ws;
    float* U  = (float*)(ws + 4194304);
    float* V  = (float*)(ws + 4325376);
    float* CI = (float*)(ws + 4456448);
    unsigned char* ADJB = (unsigned char*)(ws + 4587520);
    u32x4* AMSK = (u32x4*)(ws + 5111808);

    k_prep  <<<512 + 4096, 256, 0, stream>>>(x, adj, a1, a2, xP, U, V, CI, ADJB);
    k_expand<<<2048, 256, 0, stream>>>(ADJB, AMSK);
    k_main  <<<BCC * 32, 256, 0, stream>>>(xP, U, V, CI, AMSK, out);
}